// Round 18
// baseline (95.373 us; speedup 1.0000x reference)
//
#include <hip/hip_runtime.h>
#include <hip/hip_bf16.h>
#include <hip/hip_fp16.h>

#define NB 4
#define NS 4096
#define ND 1024
#define NP 512            // bf16 pairs per batch (ND/2)
#define LN_EPS 1e-5f

// ---------- helpers ----------
__device__ __forceinline__ int pad(int i) { return i + (i >> 4); }  // LDS anti-conflict pad

__device__ __forceinline__ float2 cadd(float2 a, float2 b) { return make_float2(a.x + b.x, a.y + b.y); }
__device__ __forceinline__ float2 csub(float2 a, float2 b) { return make_float2(a.x - b.x, a.y - b.y); }
__device__ __forceinline__ float2 cmul(float2 a, float2 b) {
  return make_float2(a.x * b.x - a.y * b.y, a.x * b.y + a.y * b.x);
}
__device__ __forceinline__ float2 cmulc(float2 a, float2 b) {  // a * conj(b)
  return make_float2(a.x * b.x + a.y * b.y, a.y * b.x - a.x * b.y);
}
__device__ __forceinline__ unsigned short f2bf(float f) {
  unsigned int u = __float_as_uint(f);
  u += 0x7FFFu + ((u >> 16) & 1u);   // RNE
  return (unsigned short)(u >> 16);
}
__device__ __forceinline__ float bf2f(unsigned int lo16) {
  return __uint_as_float(lo16 << 16);
}
__device__ __forceinline__ unsigned int packbf(float a, float b) {
  return (unsigned int)f2bf(a) | ((unsigned int)f2bf(b) << 16);
}
// fp16-pair LDS codec (math stays fp32 in registers) — validated rounds 8-10
__device__ __forceinline__ unsigned int pkh(float2 v) {
  __half2 h = __floats2half2_rn(v.x, v.y);
  return *reinterpret_cast<unsigned int*>(&h);
}
__device__ __forceinline__ float2 uph(unsigned int u) {
  __half2 h = *reinterpret_cast<__half2*>(&u);
  return __half22float2(h);
}

// reverse 3 base-16 digits of a 12-bit index
__device__ __forceinline__ int rev12(int p) {
  return ((p & 15) << 8) | (p & 240) | (p >> 8);
}

// 16-pt DFT in registers, natural order in/out. S=-1 forward, S=+1 inverse (no 1/N).
template<int S>
__device__ __forceinline__ void dft16(float2* x) {
  const float C1 = 0.9238795325112867f, S1 = 0.3826834323650898f, RT = 0.7071067811865476f;
  const float WC[10] = {1.f, C1, RT, S1, 0.f, -S1, -RT, -C1, -1.f, -C1};
  const float WS[10] = {0.f, S1, RT, C1, 1.f, C1,  RT,  S1,  0.f, -S1};
  #pragma unroll
  for (int m0 = 0; m0 < 4; ++m0) {
    float2 a = x[m0], b = x[m0 + 4], c = x[m0 + 8], d = x[m0 + 12];
    float2 t0 = cadd(a, c), t1 = csub(a, c), t2 = cadd(b, d), t3 = csub(b, d);
    float2 t3i = (S < 0) ? make_float2(t3.y, -t3.x) : make_float2(-t3.y, t3.x);
    x[m0]      = cadd(t0, t2);
    x[m0 + 4]  = cadd(t1, t3i);
    x[m0 + 8]  = csub(t0, t2);
    x[m0 + 12] = csub(t1, t3i);
  }
  #pragma unroll
  for (int r0 = 1; r0 < 4; ++r0)
    #pragma unroll
    for (int m0 = 1; m0 < 4; ++m0) {
      const int k = m0 * r0;
      const float2 w = make_float2(WC[k], (S < 0) ? -WS[k] : WS[k]);
      x[m0 + 4 * r0] = cmul(x[m0 + 4 * r0], w);
    }
  float2 y[16];
  #pragma unroll
  for (int r0 = 0; r0 < 4; ++r0) {
    float2 a = x[4 * r0], b = x[4 * r0 + 1], c = x[4 * r0 + 2], d = x[4 * r0 + 3];
    float2 t0 = cadd(a, c), t1 = csub(a, c), t2 = cadd(b, d), t3 = csub(b, d);
    float2 t3i = (S < 0) ? make_float2(t3.y, -t3.x) : make_float2(-t3.y, t3.x);
    y[r0]      = cadd(t0, t2);
    y[r0 + 4]  = cadd(t1, t3i);
    y[r0 + 8]  = csub(t0, t2);
    y[r0 + 12] = csub(t1, t3i);
  }
  #pragma unroll
  for (int i = 0; i < 16; ++i) x[i] = y[i];
}

// ---- kernel 0: fkp[p]=fk[rev]/N; TwA[i*16+j]=e^{-2pi i ij/256}; TwC[i*16+j]=e^{-2pi i ij/4096}
__global__ void kprep(const float* __restrict__ fk, float* __restrict__ fkp,
                      float2* __restrict__ TwA, float2* __restrict__ TwC) {
  const int p = blockIdx.x * 256 + threadIdx.x;
  fkp[p] = fk[rev12(p)] * (1.0f / 4096.0f);
  const float TPON = 1.5339807878856412e-3f;  // 2*pi/4096
  if (p < 256) {
    const int a = p >> 4, r = p & 15;
    float sn, cs;
    __sincosf((float)(a * r) * (TPON * 16.f), &sn, &cs);
    TwA[p] = make_float2(cs, -sn);
    __sincosf((float)(a * r) * TPON, &sn, &cs);
    TwC[p] = make_float2(cs, -sn);
  }
}

// ---- kernel 1: x[b][s][d] fp32 -> xP[b][pair][s] packed bf16x2 (pair = (d, d+1))
__global__ __launch_bounds__(256) void ktransP(const float* __restrict__ x,
                                               unsigned int* __restrict__ xP) {
  __shared__ float tile[64][65];   // [s-local][d-local]
  const int b = blockIdx.z;
  const int s0 = blockIdx.x * 64;
  const int d0 = blockIdx.y * 64;
  const int t = threadIdx.x;
  const float* xb = x + (size_t)b * NS * ND;
  #pragma unroll
  for (int p = 0; p < 4; ++p) {
    int r = (t >> 4) + p * 16;
    int c = (t & 15) * 4;
    float4 v = *reinterpret_cast<const float4*>(xb + (size_t)(s0 + r) * ND + (d0 + c));
    tile[r][c] = v.x; tile[r][c + 1] = v.y; tile[r][c + 2] = v.z; tile[r][c + 3] = v.w;
  }
  __syncthreads();
  const int pl = t >> 3;           // pair-local 0..31
  const int sc0 = (t & 7) * 8;     // s-local
  unsigned int buf[8];
  #pragma unroll
  for (int j = 0; j < 8; ++j)
    buf[j] = packbf(tile[sc0 + j][2 * pl], tile[sc0 + j][2 * pl + 1]);
  unsigned int* dst = xP + (size_t)((b * NP) + (d0 >> 1) + pl) * NS + s0 + sc0;
  *reinterpret_cast<uint4*>(dst)     = make_uint4(buf[0], buf[1], buf[2], buf[3]);
  *reinterpret_cast<uint4*>(dst + 4) = make_uint4(buf[4], buf[5], buf[6], buf[7]);
}

// ---- kernel 2: per (b, quat-group): two packed 4096-pt radix-16 FFT filters.
// fp16-pair LDS (38.9 KiB -> 4 blocks/CU), LDS twiddle tables, no atomics, bf16-pair global I/O.
__global__ __launch_bounds__(512, 4) void kfft(unsigned int* __restrict__ xP,
                                               const float* __restrict__ fkp,
                                               const float2* __restrict__ TwAg,
                                               const float2* __restrict__ TwCg,
                                               const float* __restrict__ R) {
  extern __shared__ unsigned char smem[];
  unsigned int* zdyn = (unsigned int*)smem;          // 2 x 4352 uint (half2) = 34816 B
  float2* twl = (float2*)(smem + 34816);             // [0..255]=TwA, [256..511]=TwC (4096 B)
  const int t = threadIdx.x;
  const int h = t >> 8;              // half: pair q*2+h = cols (2h, 2h+1)
  const int tt = t & 255;
  const int q = blockIdx.x;
  const int b = blockIdx.y;
  const unsigned int* rowP = xP + (size_t)(b * NP + q * 2 + h) * NS;
  unsigned int* zz = zdyn + (size_t)h * 4352;
  const int ta = tt >> 4, tc = tt & 15;
  float2 x[16];

  // stage twiddle tables into LDS (512 threads cover 512 entries)
  twl[t] = (t < 256) ? TwAg[t] : TwCg[t - 256];

  // ---- F1 (L=256): bf16-pair load (z = c0 + i c1) -> DFT16 -> table twiddle -> LDS
  #pragma unroll
  for (int m = 0; m < 16; ++m) {
    unsigned int u = rowP[tt + 256 * m];
    x[m] = make_float2(bf2f(u & 0xffffu), bf2f(u >> 16));
  }
  dft16<-1>(x);
  __syncthreads();   // twl ready
  zz[pad(tt)] = pkh(x[0]);
  #pragma unroll
  for (int r = 1; r < 16; ++r) {
    float2 tw = cmul(twl[r * 16 + ta], twl[256 + r * 16 + tc]);  // w4096^{tt r}
    zz[pad(tt + 256 * r)] = pkh(cmul(x[r], tw));
  }
  __syncthreads();
  // ---- F2 (L=16): twiddle w256^{j r} = TwA[j r]
  {
    const int bs = 256 * (tt >> 4) + (tt & 15);
    const int j = tt & 15;
    #pragma unroll
    for (int m = 0; m < 16; ++m) x[m] = uph(zz[pad(bs + 16 * m)]);
    dft16<-1>(x);
    zz[pad(bs)] = pkh(x[0]);
    #pragma unroll
    for (int r = 1; r < 16; ++r) zz[pad(bs + 16 * r)] = pkh(cmul(x[r], twl[r * 16 + j]));
  }
  __syncthreads();
  // ---- F3 (L=1) + filter (digit-reversed domain) + I1 (L=1), in registers
  {
    const int bs = 16 * tt;
    #pragma unroll
    for (int m = 0; m < 16; ++m) x[m] = uph(zz[pad(bs + m)]);
    dft16<-1>(x);
    #pragma unroll
    for (int r4 = 0; r4 < 4; ++r4) {
      float4 kv = *reinterpret_cast<const float4*>(fkp + bs + 4 * r4);
      x[4 * r4 + 0].x *= kv.x; x[4 * r4 + 0].y *= kv.x;
      x[4 * r4 + 1].x *= kv.y; x[4 * r4 + 1].y *= kv.y;
      x[4 * r4 + 2].x *= kv.z; x[4 * r4 + 2].y *= kv.z;
      x[4 * r4 + 3].x *= kv.w; x[4 * r4 + 3].y *= kv.w;
    }
    dft16<1>(x);
    #pragma unroll
    for (int r = 0; r < 16; ++r) zz[pad(bs + r)] = pkh(x[r]);
  }
  __syncthreads();
  // ---- I2 (L=16): input twiddle conj(TwA[j m])
  {
    const int bs = 256 * (tt >> 4) + (tt & 15);
    const int j = tt & 15;
    x[0] = uph(zz[pad(bs)]);
    #pragma unroll
    for (int m = 1; m < 16; ++m) x[m] = cmulc(uph(zz[pad(bs + 16 * m)]), twl[m * 16 + j]);
    dft16<1>(x);
    #pragma unroll
    for (int r = 0; r < 16; ++r) zz[pad(bs + 16 * r)] = pkh(x[r]);
  }
  __syncthreads();
  // ---- I3 (L=256): input twiddle conj(TwA[ta m] * TwC[tc m]); output natural order
  {
    x[0] = uph(zz[pad(tt)]);
    #pragma unroll
    for (int m = 1; m < 16; ++m)
      x[m] = cmulc(cmulc(uph(zz[pad(tt + 256 * m)]), twl[m * 16 + ta]), twl[256 + m * 16 + tc]);
    dft16<1>(x);
    #pragma unroll
    for (int r = 0; r < 16; ++r) zz[pad(tt + 256 * r)] = pkh(x[r]);
  }
  __syncthreads();
  // ---- rotation + bf16-pair write-back (all 512 threads over s); NO atomics
  const float r00 = R[0],  r01 = R[1],  r02 = R[2],  r03 = R[3];
  const float r10 = R[4],  r11 = R[5],  r12 = R[6],  r13 = R[7];
  const float r20 = R[8],  r21 = R[9],  r22 = R[10], r23 = R[11];
  const float r30 = R[12], r31 = R[13], r32 = R[14], r33 = R[15];
  unsigned int* row0 = xP + (size_t)(b * NP + q * 2) * NS;
  unsigned int* row1 = row0 + NS;
  #pragma unroll
  for (int k = 0; k < 8; ++k) {
    const int s = t + 512 * k;
    float2 v0 = uph(zdyn[pad(s)]);
    float2 v1 = uph(zdyn[4352 + pad(s)]);
    float c0 = v0.x, c1 = v0.y, c2 = v1.x, c3 = v1.y;
    float o0 = r00 * c0 + r01 * c1 + r02 * c2 + r03 * c3;
    float o1 = r10 * c0 + r11 * c1 + r12 * c2 + r13 * c3;
    float o2 = r20 * c0 + r21 * c1 + r22 * c2 + r23 * c3;
    float o3 = r30 * c0 + r31 * c1 + r32 * c2 + r33 * c3;
    row0[s] = packbf(o0, o1);
    row1[s] = packbf(o2, o3);
  }
}

// ---- kernel 2b: LN stats from bf16 pairs (coalesced, deterministic, no atomics)
__global__ __launch_bounds__(256) void kstatsP(const unsigned int* __restrict__ xP,
                                               float* __restrict__ ssum,
                                               float* __restrict__ ssq) {
  const int b = blockIdx.y;
  const int s0 = blockIdx.x * 64;
  const int w = threadIdx.x >> 6;     // wave 0..3
  const int l = threadIdx.x & 63;     // s-lane
  const unsigned int* src = xP + (size_t)b * NP * NS + s0 + l;
  float as = 0.f, aq = 0.f;
  for (int p = w * 4; p < NP; p += 16) {
    #pragma unroll
    for (int j = 0; j < 4; ++j) {
      unsigned int u = src[(size_t)(p + j) * NS];
      float v0 = bf2f(u & 0xffffu), v1 = bf2f(u >> 16);
      as += v0 + v1;
      aq += v0 * v0 + v1 * v1;
    }
  }
  __shared__ float rs[4][64], rq[4][64];
  rs[w][l] = as;
  rq[w][l] = aq;
  __syncthreads();
  if (w == 0) {
    ssum[b * NS + s0 + l] = (rs[0][l] + rs[1][l]) + (rs[2][l] + rs[3][l]);
    ssq[b * NS + s0 + l]  = (rq[0][l] + rq[1][l]) + (rq[2][l] + rq[3][l]);
  }
}

// ---- kernel 3: unpack + transpose back + LayerNorm apply  xP[b][pair][s] -> out[b][s][d]
__global__ __launch_bounds__(256) void kapplyP(const unsigned int* __restrict__ xP,
                                               const float* __restrict__ ssum,
                                               const float* __restrict__ ssq,
                                               const float* __restrict__ gam,
                                               const float* __restrict__ bet,
                                               float* __restrict__ out) {
  __shared__ float tile[64][65];   // [d-local][s-local]
  const int b = blockIdx.z;
  const int s0 = blockIdx.x * 64;
  const int d0 = blockIdx.y * 64;
  const int t = threadIdx.x;
  const int pl = t >> 3;           // pair-local 0..31
  const int sc0 = (t & 7) * 8;
  const unsigned int* src = xP + (size_t)(b * NP + (d0 >> 1) + pl) * NS + s0 + sc0;
  uint4 u0 = *reinterpret_cast<const uint4*>(src);
  uint4 u1 = *reinterpret_cast<const uint4*>(src + 4);
  const unsigned int uu[8] = {u0.x, u0.y, u0.z, u0.w, u1.x, u1.y, u1.z, u1.w};
  #pragma unroll
  for (int j = 0; j < 8; ++j) {
    tile[2 * pl][sc0 + j]     = bf2f(uu[j] & 0xffffu);
    tile[2 * pl + 1][sc0 + j] = bf2f(uu[j] >> 16);
  }
  __syncthreads();
  float* dst = out + ((size_t)b * NS + s0) * ND + d0;
  #pragma unroll
  for (int p = 0; p < 4; ++p) {
    int sr = (t >> 4) + p * 16;     // s-local
    int s = s0 + sr;
    float mean = ssum[b * NS + s] * (1.0f / ND);
    float var = ssq[b * NS + s] * (1.0f / ND) - mean * mean;
    float inv = rsqrtf(var + LN_EPS);
    int dc = (t & 15) * 4;
    float4 g4 = *reinterpret_cast<const float4*>(gam + d0 + dc);
    float4 b4 = *reinterpret_cast<const float4*>(bet + d0 + dc);
    float4 o;
    o.x = (tile[dc + 0][sr] - mean) * inv * g4.x + b4.x;
    o.y = (tile[dc + 1][sr] - mean) * inv * g4.y + b4.y;
    o.z = (tile[dc + 2][sr] - mean) * inv * g4.z + b4.z;
    o.w = (tile[dc + 3][sr] - mean) * inv * g4.w + b4.w;
    *reinterpret_cast<float4*>(dst + (size_t)sr * ND + dc) = o;
  }
}

extern "C" void kernel_launch(void* const* d_in, const int* in_sizes, int n_in,
                              void* d_out, int out_size, void* d_ws, size_t ws_size,
                              hipStream_t stream) {
  const float* x  = (const float*)d_in[0];
  const float* R  = (const float*)d_in[1];
  const float* fk = (const float*)d_in[2];
  const float* gm = (const float*)d_in[3];
  const float* bt = (const float*)d_in[4];
  float* out = (float*)d_out;

  char* ws = (char*)d_ws;
  unsigned int* xP = (unsigned int*)ws;                              // 32 MiB
  float*  ssum = (float*)(ws + (size_t)NB * NP * NS * 4);            // 64 KiB
  float*  ssq  = ssum + NB * NS;                                     // 64 KiB
  float*  fkp  = ssq + NB * NS;                                      // 16 KiB
  float2* TwA  = (float2*)(fkp + NS);                                // 2 KiB
  float2* TwC  = TwA + 256;                                          // 2 KiB

  (void)hipFuncSetAttribute((const void*)kfft,
                            hipFuncAttributeMaxDynamicSharedMemorySize, 38912);

  kprep<<<16, 256, 0, stream>>>(fk, fkp, TwA, TwC);
  ktransP<<<dim3(NS / 64, ND / 64, NB), 256, 0, stream>>>(x, xP);
  kfft<<<dim3(ND / 4, NB), 512, 38912, stream>>>(xP, fkp, TwA, TwC, R);
  kstatsP<<<dim3(NS / 64, NB), 256, 0, stream>>>(xP, ssum, ssq);
  kapplyP<<<dim3(NS / 64, ND / 64, NB), 256, 0, stream>>>(xP, ssum, ssq, gm, bt, out);
}

// Round 19
// 93.717 us; speedup vs baseline: 1.0177x; 1.0177x over previous
//
#include <hip/hip_runtime.h>
#include <hip/hip_bf16.h>

#define NB 4
#define NS 4096
#define ND 1024
#define NP 512            // bf16 pairs per batch (ND/2)
#define LN_EPS 1e-5f

// ---------- helpers ----------
__device__ __forceinline__ int pad(int i) { return i + (i >> 4); }  // LDS anti-conflict pad

__device__ __forceinline__ float2 cadd(float2 a, float2 b) { return make_float2(a.x + b.x, a.y + b.y); }
__device__ __forceinline__ float2 csub(float2 a, float2 b) { return make_float2(a.x - b.x, a.y - b.y); }
__device__ __forceinline__ float2 cmul(float2 a, float2 b) {
  return make_float2(a.x * b.x - a.y * b.y, a.x * b.y + a.y * b.x);
}
__device__ __forceinline__ float2 cmulc(float2 a, float2 b) {  // a * conj(b)
  return make_float2(a.x * b.x + a.y * b.y, a.y * b.x - a.x * b.y);
}
__device__ __forceinline__ unsigned short f2bf(float f) {
  unsigned int u = __float_as_uint(f);
  u += 0x7FFFu + ((u >> 16) & 1u);   // RNE
  return (unsigned short)(u >> 16);
}
__device__ __forceinline__ float bf2f(unsigned int lo16) {
  return __uint_as_float(lo16 << 16);
}
__device__ __forceinline__ unsigned int packbf(float a, float b) {
  return (unsigned int)f2bf(a) | ((unsigned int)f2bf(b) << 16);
}

// reverse 3 base-16 digits of a 12-bit index
__device__ __forceinline__ int rev12(int p) {
  return ((p & 15) << 8) | (p & 240) | (p >> 8);
}

// 16-pt DFT in registers, natural order in/out. S=-1 forward, S=+1 inverse (no 1/N).
template<int S>
__device__ __forceinline__ void dft16(float2* x) {
  const float C1 = 0.9238795325112867f, S1 = 0.3826834323650898f, RT = 0.7071067811865476f;
  const float WC[10] = {1.f, C1, RT, S1, 0.f, -S1, -RT, -C1, -1.f, -C1};
  const float WS[10] = {0.f, S1, RT, C1, 1.f, C1,  RT,  S1,  0.f, -S1};
  #pragma unroll
  for (int m0 = 0; m0 < 4; ++m0) {
    float2 a = x[m0], b = x[m0 + 4], c = x[m0 + 8], d = x[m0 + 12];
    float2 t0 = cadd(a, c), t1 = csub(a, c), t2 = cadd(b, d), t3 = csub(b, d);
    float2 t3i = (S < 0) ? make_float2(t3.y, -t3.x) : make_float2(-t3.y, t3.x);
    x[m0]      = cadd(t0, t2);
    x[m0 + 4]  = cadd(t1, t3i);
    x[m0 + 8]  = csub(t0, t2);
    x[m0 + 12] = csub(t1, t3i);
  }
  #pragma unroll
  for (int r0 = 1; r0 < 4; ++r0)
    #pragma unroll
    for (int m0 = 1; m0 < 4; ++m0) {
      const int k = m0 * r0;
      const float2 w = make_float2(WC[k], (S < 0) ? -WS[k] : WS[k]);
      x[m0 + 4 * r0] = cmul(x[m0 + 4 * r0], w);
    }
  float2 y[16];
  #pragma unroll
  for (int r0 = 0; r0 < 4; ++r0) {
    float2 a = x[4 * r0], b = x[4 * r0 + 1], c = x[4 * r0 + 2], d = x[4 * r0 + 3];
    float2 t0 = cadd(a, c), t1 = csub(a, c), t2 = cadd(b, d), t3 = csub(b, d);
    float2 t3i = (S < 0) ? make_float2(t3.y, -t3.x) : make_float2(-t3.y, t3.x);
    y[r0]      = cadd(t0, t2);
    y[r0 + 4]  = cadd(t1, t3i);
    y[r0 + 8]  = csub(t0, t2);
    y[r0 + 12] = csub(t1, t3i);
  }
  #pragma unroll
  for (int i = 0; i < 16; ++i) x[i] = y[i];
}

// ---- kernel 0: fkp[p]=fk[rev]/N; TwA[i*16+j]=e^{-2pi i ij/256}; TwC[i*16+j]=e^{-2pi i ij/4096}
__global__ void kprep(const float* __restrict__ fk, float* __restrict__ fkp,
                      float2* __restrict__ TwA, float2* __restrict__ TwC) {
  const int p = blockIdx.x * 256 + threadIdx.x;
  fkp[p] = fk[rev12(p)] * (1.0f / 4096.0f);
  const float TPON = 1.5339807878856412e-3f;  // 2*pi/4096
  if (p < 256) {
    const int a = p >> 4, r = p & 15;
    float sn, cs;
    __sincosf((float)(a * r) * (TPON * 16.f), &sn, &cs);
    TwA[p] = make_float2(cs, -sn);
    __sincosf((float)(a * r) * TPON, &sn, &cs);
    TwC[p] = make_float2(cs, -sn);
  }
}

// ---- kernel 1: x[b][s][d] fp32 -> xP[b][pair][s] packed bf16x2 (pair = (d, d+1))
__global__ __launch_bounds__(256) void ktransP(const float* __restrict__ x,
                                               unsigned int* __restrict__ xP) {
  __shared__ float tile[64][65];   // [s-local][d-local]
  const int b = blockIdx.z;
  const int s0 = blockIdx.x * 64;
  const int d0 = blockIdx.y * 64;
  const int t = threadIdx.x;
  const float* xb = x + (size_t)b * NS * ND;
  #pragma unroll
  for (int p = 0; p < 4; ++p) {
    int r = (t >> 4) + p * 16;
    int c = (t & 15) * 4;
    float4 v = *reinterpret_cast<const float4*>(xb + (size_t)(s0 + r) * ND + (d0 + c));
    tile[r][c] = v.x; tile[r][c + 1] = v.y; tile[r][c + 2] = v.z; tile[r][c + 3] = v.w;
  }
  __syncthreads();
  const int pl = t >> 3;           // pair-local 0..31
  const int sc0 = (t & 7) * 8;     // s-local
  unsigned int buf[8];
  #pragma unroll
  for (int j = 0; j < 8; ++j)
    buf[j] = packbf(tile[sc0 + j][2 * pl], tile[sc0 + j][2 * pl + 1]);
  unsigned int* dst = xP + (size_t)((b * NP) + (d0 >> 1) + pl) * NS + s0 + sc0;
  *reinterpret_cast<uint4*>(dst)     = make_uint4(buf[0], buf[1], buf[2], buf[3]);
  *reinterpret_cast<uint4*>(dst + 4) = make_uint4(buf[4], buf[5], buf[6], buf[7]);
}

// ---- kernel 2: per (b, quat-group): two packed 4096-pt radix-16 FFT filters.
// fp32 float2 LDS, LDS twiddle tables, no atomics, bf16-pair global I/O. (best measured config)
__global__ __launch_bounds__(512, 4) void kfft(unsigned int* __restrict__ xP,
                                               const float* __restrict__ fkp,
                                               const float2* __restrict__ TwAg,
                                               const float2* __restrict__ TwCg,
                                               const float* __restrict__ R) {
  extern __shared__ unsigned char smem[];
  float2* zdyn = (float2*)smem;                      // 2 x 4352 float2 = 69632 B
  float2* twl = (float2*)(smem + 69632);             // [0..255]=TwA, [256..511]=TwC (4096 B)
  const int t = threadIdx.x;
  const int h = t >> 8;              // half: pair q*2+h = cols (2h, 2h+1)
  const int tt = t & 255;
  const int q = blockIdx.x;
  const int b = blockIdx.y;
  const unsigned int* rowP = xP + (size_t)(b * NP + q * 2 + h) * NS;
  float2* zz = zdyn + (size_t)h * 4352;
  const int ta = tt >> 4, tc = tt & 15;
  float2 x[16];

  // stage twiddle tables into LDS (512 threads cover 512 entries)
  twl[t] = (t < 256) ? TwAg[t] : TwCg[t - 256];

  // ---- F1 (L=256): bf16-pair load (z = c0 + i c1) -> DFT16 -> table twiddle -> LDS
  #pragma unroll
  for (int m = 0; m < 16; ++m) {
    unsigned int u = rowP[tt + 256 * m];
    x[m] = make_float2(bf2f(u & 0xffffu), bf2f(u >> 16));
  }
  dft16<-1>(x);
  __syncthreads();   // twl ready
  zz[pad(tt)] = x[0];
  #pragma unroll
  for (int r = 1; r < 16; ++r) {
    float2 tw = cmul(twl[r * 16 + ta], twl[256 + r * 16 + tc]);  // w4096^{tt r}
    zz[pad(tt + 256 * r)] = cmul(x[r], tw);
  }
  __syncthreads();
  // ---- F2 (L=16): twiddle w256^{j r} = TwA[j r]
  {
    const int bs = 256 * (tt >> 4) + (tt & 15);
    const int j = tt & 15;
    #pragma unroll
    for (int m = 0; m < 16; ++m) x[m] = zz[pad(bs + 16 * m)];
    dft16<-1>(x);
    zz[pad(bs)] = x[0];
    #pragma unroll
    for (int r = 1; r < 16; ++r) zz[pad(bs + 16 * r)] = cmul(x[r], twl[r * 16 + j]);
  }
  __syncthreads();
  // ---- F3 (L=1) + filter (digit-reversed domain) + I1 (L=1), in registers
  {
    const int bs = 16 * tt;
    #pragma unroll
    for (int m = 0; m < 16; ++m) x[m] = zz[pad(bs + m)];
    dft16<-1>(x);
    #pragma unroll
    for (int r4 = 0; r4 < 4; ++r4) {
      float4 kv = *reinterpret_cast<const float4*>(fkp + bs + 4 * r4);
      x[4 * r4 + 0].x *= kv.x; x[4 * r4 + 0].y *= kv.x;
      x[4 * r4 + 1].x *= kv.y; x[4 * r4 + 1].y *= kv.y;
      x[4 * r4 + 2].x *= kv.z; x[4 * r4 + 2].y *= kv.z;
      x[4 * r4 + 3].x *= kv.w; x[4 * r4 + 3].y *= kv.w;
    }
    dft16<1>(x);
    #pragma unroll
    for (int r = 0; r < 16; ++r) zz[pad(bs + r)] = x[r];
  }
  __syncthreads();
  // ---- I2 (L=16): input twiddle conj(TwA[j m])
  {
    const int bs = 256 * (tt >> 4) + (tt & 15);
    const int j = tt & 15;
    x[0] = zz[pad(bs)];
    #pragma unroll
    for (int m = 1; m < 16; ++m) x[m] = cmulc(zz[pad(bs + 16 * m)], twl[m * 16 + j]);
    dft16<1>(x);
    #pragma unroll
    for (int r = 0; r < 16; ++r) zz[pad(bs + 16 * r)] = x[r];
  }
  __syncthreads();
  // ---- I3 (L=256): input twiddle conj(TwA[ta m] * TwC[tc m]); output natural order
  {
    x[0] = zz[pad(tt)];
    #pragma unroll
    for (int m = 1; m < 16; ++m)
      x[m] = cmulc(cmulc(zz[pad(tt + 256 * m)], twl[m * 16 + ta]), twl[256 + m * 16 + tc]);
    dft16<1>(x);
    #pragma unroll
    for (int r = 0; r < 16; ++r) zz[pad(tt + 256 * r)] = x[r];
  }
  __syncthreads();
  // ---- rotation + bf16-pair write-back (all 512 threads over s); NO atomics
  const float r00 = R[0],  r01 = R[1],  r02 = R[2],  r03 = R[3];
  const float r10 = R[4],  r11 = R[5],  r12 = R[6],  r13 = R[7];
  const float r20 = R[8],  r21 = R[9],  r22 = R[10], r23 = R[11];
  const float r30 = R[12], r31 = R[13], r32 = R[14], r33 = R[15];
  unsigned int* row0 = xP + (size_t)(b * NP + q * 2) * NS;
  unsigned int* row1 = row0 + NS;
  #pragma unroll
  for (int k = 0; k < 8; ++k) {
    const int s = t + 512 * k;
    float2 v0 = zdyn[pad(s)];
    float2 v1 = zdyn[4352 + pad(s)];
    float c0 = v0.x, c1 = v0.y, c2 = v1.x, c3 = v1.y;
    float o0 = r00 * c0 + r01 * c1 + r02 * c2 + r03 * c3;
    float o1 = r10 * c0 + r11 * c1 + r12 * c2 + r13 * c3;
    float o2 = r20 * c0 + r21 * c1 + r22 * c2 + r23 * c3;
    float o3 = r30 * c0 + r31 * c1 + r32 * c2 + r33 * c3;
    row0[s] = packbf(o0, o1);
    row1[s] = packbf(o2, o3);
  }
}

// ---- kernel 2b: LN stats from bf16 pairs (coalesced, deterministic, no atomics)
__global__ __launch_bounds__(256) void kstatsP(const unsigned int* __restrict__ xP,
                                               float* __restrict__ ssum,
                                               float* __restrict__ ssq) {
  const int b = blockIdx.y;
  const int s0 = blockIdx.x * 64;
  const int w = threadIdx.x >> 6;     // wave 0..3
  const int l = threadIdx.x & 63;     // s-lane
  const unsigned int* src = xP + (size_t)b * NP * NS + s0 + l;
  float as = 0.f, aq = 0.f;
  for (int p = w * 4; p < NP; p += 16) {
    #pragma unroll
    for (int j = 0; j < 4; ++j) {
      unsigned int u = src[(size_t)(p + j) * NS];
      float v0 = bf2f(u & 0xffffu), v1 = bf2f(u >> 16);
      as += v0 + v1;
      aq += v0 * v0 + v1 * v1;
    }
  }
  __shared__ float rs[4][64], rq[4][64];
  rs[w][l] = as;
  rq[w][l] = aq;
  __syncthreads();
  if (w == 0) {
    ssum[b * NS + s0 + l] = (rs[0][l] + rs[1][l]) + (rs[2][l] + rs[3][l]);
    ssq[b * NS + s0 + l]  = (rq[0][l] + rq[1][l]) + (rq[2][l] + rq[3][l]);
  }
}

// ---- kernel 3: unpack + transpose back + LayerNorm apply  xP[b][pair][s] -> out[b][s][d]
__global__ __launch_bounds__(256) void kapplyP(const unsigned int* __restrict__ xP,
                                               const float* __restrict__ ssum,
                                               const float* __restrict__ ssq,
                                               const float* __restrict__ gam,
                                               const float* __restrict__ bet,
                                               float* __restrict__ out) {
  __shared__ float tile[64][65];   // [d-local][s-local]
  const int b = blockIdx.z;
  const int s0 = blockIdx.x * 64;
  const int d0 = blockIdx.y * 64;
  const int t = threadIdx.x;
  const int pl = t >> 3;           // pair-local 0..31
  const int sc0 = (t & 7) * 8;
  const unsigned int* src = xP + (size_t)(b * NP + (d0 >> 1) + pl) * NS + s0 + sc0;
  uint4 u0 = *reinterpret_cast<const uint4*>(src);
  uint4 u1 = *reinterpret_cast<const uint4*>(src + 4);
  const unsigned int uu[8] = {u0.x, u0.y, u0.z, u0.w, u1.x, u1.y, u1.z, u1.w};
  #pragma unroll
  for (int j = 0; j < 8; ++j) {
    tile[2 * pl][sc0 + j]     = bf2f(uu[j] & 0xffffu);
    tile[2 * pl + 1][sc0 + j] = bf2f(uu[j] >> 16);
  }
  __syncthreads();
  float* dst = out + ((size_t)b * NS + s0) * ND + d0;
  #pragma unroll
  for (int p = 0; p < 4; ++p) {
    int sr = (t >> 4) + p * 16;     // s-local
    int s = s0 + sr;
    float mean = ssum[b * NS + s] * (1.0f / ND);
    float var = ssq[b * NS + s] * (1.0f / ND) - mean * mean;
    float inv = rsqrtf(var + LN_EPS);
    int dc = (t & 15) * 4;
    float4 g4 = *reinterpret_cast<const float4*>(gam + d0 + dc);
    float4 b4 = *reinterpret_cast<const float4*>(bet + d0 + dc);
    float4 o;
    o.x = (tile[dc + 0][sr] - mean) * inv * g4.x + b4.x;
    o.y = (tile[dc + 1][sr] - mean) * inv * g4.y + b4.y;
    o.z = (tile[dc + 2][sr] - mean) * inv * g4.z + b4.z;
    o.w = (tile[dc + 3][sr] - mean) * inv * g4.w + b4.w;
    *reinterpret_cast<float4*>(dst + (size_t)sr * ND + dc) = o;
  }
}

extern "C" void kernel_launch(void* const* d_in, const int* in_sizes, int n_in,
                              void* d_out, int out_size, void* d_ws, size_t ws_size,
                              hipStream_t stream) {
  const float* x  = (const float*)d_in[0];
  const float* R  = (const float*)d_in[1];
  const float* fk = (const float*)d_in[2];
  const float* gm = (const float*)d_in[3];
  const float* bt = (const float*)d_in[4];
  float* out = (float*)d_out;

  char* ws = (char*)d_ws;
  unsigned int* xP = (unsigned int*)ws;                              // 32 MiB
  float*  ssum = (float*)(ws + (size_t)NB * NP * NS * 4);            // 64 KiB
  float*  ssq  = ssum + NB * NS;                                     // 64 KiB
  float*  fkp  = ssq + NB * NS;                                      // 16 KiB
  float2* TwA  = (float2*)(fkp + NS);                                // 2 KiB
  float2* TwC  = TwA + 256;                                          // 2 KiB

  (void)hipFuncSetAttribute((const void*)kfft,
                            hipFuncAttributeMaxDynamicSharedMemorySize, 73728);

  kprep<<<16, 256, 0, stream>>>(fk, fkp, TwA, TwC);
  ktransP<<<dim3(NS / 64, ND / 64, NB), 256, 0, stream>>>(x, xP);
  kfft<<<dim3(ND / 4, NB), 512, 73728, stream>>>(xP, fkp, TwA, TwC, R);
  kstatsP<<<dim3(NS / 64, NB), 256, 0, stream>>>(xP, ssum, ssq);
  kapplyP<<<dim3(NS / 64, ND / 64, NB), 256, 0, stream>>>(xP, ssum, ssq, gm, bt, out);
}